// Round 4
// baseline (385.748 us; speedup 1.0000x reference)
//
#include <hip/hip_runtime.h>
#include <stdint.h>

// NeiAttention: B=512, N=32, S=16, EF=64, NF=D=128, K=192
// v6: ZERO-barrier main loop. Each wave owns whole (b,n) tiles:
//   - A-fragments loaded straight from global into regs (lane (quad,s)
//     needs feat[s][q*32+quad*8..+7] = contiguous 32B chunks -> 12 dwordx4)
//   - W packed ONCE per block into LDS as bf16 B-fragments (48 KB, one
//     prologue barrier, W reads are L2-hits)
//   - v(16x128) lives entirely in 32 acc VGPRs; alpha/softmax/weighted sum
//     via shfl butterflies (no lds_v, no lds_alpha, no spill-prone caps)
// launch_bounds(256,3): 170-reg cap (live ~145), LDS 48KB -> 3 blocks/CU.

typedef __attribute__((ext_vector_type(8))) short short8;
typedef __attribute__((ext_vector_type(4))) float float4_t;
typedef __attribute__((ext_vector_type(4))) unsigned short ushort4_t;

#define GRID_ 1024
#define TPW_  4    // tiles per wave: 1024 blocks * 4 waves * 4 = 16384 = B*N

__device__ __forceinline__ unsigned short f2bf(float f) {
    uint32_t u = __float_as_uint(f);
    u += 0x7fffu + ((u >> 16) & 1u);   // RNE
    return (unsigned short)(u >> 16);
}

__global__ __launch_bounds__(256, 3) void nei_attn_kernel(
    const float* __restrict__ x,
    const float* __restrict__ rel,
    const float* __restrict__ node,
    const float* __restrict__ W,
    const float* __restrict__ bias,
    float* __restrict__ out)
{
    // W as bf16 B-fragments: slot = (ct*6+q)*64 + lane, 8 ushort each = 48 KB
    __shared__ __align__(16) unsigned short lds_w[3072 * 8];

    const int t    = threadIdx.x;
    const int lane = t & 63;
    const int wv   = t >> 6;        // wave 0..3
    const int c    = lane & 15;     // col within 16-tile  (also row s for A)
    const int quad = lane >> 4;     // k-subblock for A/B frags

    // ---- prologue: pack W (128x192 f32) -> B-frag bf16 layout in LDS ----
    // B-frag for (ct,q): lane (quad,cl) holds W[ct*16+cl][q*32+quad*8 .. +7]
    #pragma unroll
    for (int i = 0; i < 12; ++i) {
        const int slot = t + i * 256;              // 0..3071
        const int ct  = slot / 384;
        const int rem = slot - ct * 384;
        const int q   = rem >> 6;
        const int l   = rem & 63;
        const int row = ct * 16 + (l & 15);
        const int kb  = q * 32 + (l >> 4) * 8;
        const float* wp = W + row * 192 + kb;
        float4_t w0 = *(const float4_t*)wp;
        float4_t w1 = *(const float4_t*)(wp + 4);
        ushort4_t u0, u1;
        u0[0] = f2bf(w0.x); u0[1] = f2bf(w0.y); u0[2] = f2bf(w0.z); u0[3] = f2bf(w0.w);
        u1[0] = f2bf(w1.x); u1[1] = f2bf(w1.y); u1[2] = f2bf(w1.z); u1[3] = f2bf(w1.w);
        *(ushort4_t*)&lds_w[slot * 8]     = u0;
        *(ushort4_t*)&lds_w[slot * 8 + 4] = u1;
    }

    // bias per lane: column d = ct*16 + c (same for all rows) -- loop-invariant
    float bv[8];
    #pragma unroll
    for (int ct = 0; ct < 8; ++ct) bv[ct] = bias[ct * 16 + c];

    __syncthreads();   // the ONLY barrier in the kernel

    int idx = (blockIdx.x * 4 + wv) * TPW_;

    // per-tile A loads: lane (quad, s=c) reads feat[s][q*32+quad*8..+7], q=0..5
    // rel  float offs: s*64  + {0,32}       + quad*8   (q=0,1)
    // node float offs: s*128 + {0,32,64,96} + quad*8   (q=2..5)
    #define LOAD_TILE(BUF, IDX) {                                          \
        const float* pr = rel  + (IDX) * 1024 + c * 64  + quad * 8;        \
        const float* pn = node + (IDX) * 2048 + c * 128 + quad * 8;        \
        BUF[0]  = *(const float4_t*)pr;        BUF[1]  = *(const float4_t*)(pr + 4);   \
        BUF[2]  = *(const float4_t*)(pr + 32); BUF[3]  = *(const float4_t*)(pr + 36);  \
        BUF[4]  = *(const float4_t*)pn;        BUF[5]  = *(const float4_t*)(pn + 4);   \
        BUF[6]  = *(const float4_t*)(pn + 32); BUF[7]  = *(const float4_t*)(pn + 36);  \
        BUF[8]  = *(const float4_t*)(pn + 64); BUF[9]  = *(const float4_t*)(pn + 68);  \
        BUF[10] = *(const float4_t*)(pn + 96); BUF[11] = *(const float4_t*)(pn + 100); }

    float4_t buf[12];
    LOAD_TILE(buf, idx)

    #pragma unroll 1
    for (int it = 0; it < TPW_; ++it) {
        // x values this lane needs: x[idx*128 + ct*16 + c] (issued early)
        float xv[8];
        #pragma unroll
        for (int ct = 0; ct < 8; ++ct) xv[ct] = x[idx * 128 + ct * 16 + c];

        // ---- convert arrived buf -> A-frags (frees buf for prefetch) ----
        short8 af[6];
        #pragma unroll
        for (int q = 0; q < 6; ++q) {
            float4_t lo = buf[2 * q], hi = buf[2 * q + 1];
            short8 f;
            f[0] = (short)f2bf(lo.x); f[1] = (short)f2bf(lo.y);
            f[2] = (short)f2bf(lo.z); f[3] = (short)f2bf(lo.w);
            f[4] = (short)f2bf(hi.x); f[5] = (short)f2bf(hi.y);
            f[6] = (short)f2bf(hi.z); f[7] = (short)f2bf(hi.w);
            af[q] = f;
        }

        // ---- prefetch next tile (hidden under MFMA + epilogue) ----
        if (it + 1 < TPW_) LOAD_TILE(buf, idx + 1)

        // ---- projection: v[16][128] in regs; lane -> v[quad*4+r][ct*16+c] ----
        float4_t acc[8];
        #pragma unroll
        for (int ct = 0; ct < 8; ++ct) acc[ct] = (float4_t){0.f, 0.f, 0.f, 0.f};
        #pragma unroll
        for (int ct = 0; ct < 8; ++ct) {
            #pragma unroll
            for (int q = 0; q < 6; ++q) {
                short8 wf = *(const short8*)&lds_w[(ct * 6 + q) * 512 + lane * 8];
                acc[ct] = __builtin_amdgcn_mfma_f32_16x16x32_bf16(af[q], wf, acc[ct], 0, 0, 0);
            }
        }
        #pragma unroll
        for (int ct = 0; ct < 8; ++ct) {
            #pragma unroll
            for (int r = 0; r < 4; ++r) acc[ct][r] += bv[ct];
        }

        // ---- alpha partials for rows quad*4+r: sum_d x[d]*v[row][d] ----
        float p0 = 0.f, p1 = 0.f, p2 = 0.f, p3 = 0.f;
        #pragma unroll
        for (int ct = 0; ct < 8; ++ct) {
            p0 += xv[ct] * acc[ct][0];
            p1 += xv[ct] * acc[ct][1];
            p2 += xv[ct] * acc[ct][2];
            p3 += xv[ct] * acc[ct][3];
        }
        // reduce over the 16 cols of this quad-group
        #pragma unroll
        for (int m = 1; m <= 8; m <<= 1) {
            p0 += __shfl_xor(p0, m);
            p1 += __shfl_xor(p1, m);
            p2 += __shfl_xor(p2, m);
            p3 += __shfl_xor(p3, m);
        }
        const float norm = 0.08838834764831845f;   // 1/sqrt(128)
        p0 *= norm; p1 *= norm; p2 *= norm; p3 *= norm;
        // gather the other quads' rows (alpha order irrelevant for max/den)
        float q10 = __shfl_xor(p0, 16), q11 = __shfl_xor(p1, 16),
              q12 = __shfl_xor(p2, 16), q13 = __shfl_xor(p3, 16);
        float q20 = __shfl_xor(p0, 32), q21 = __shfl_xor(p1, 32),
              q22 = __shfl_xor(p2, 32), q23 = __shfl_xor(p3, 32);
        float q30 = __shfl_xor(p0, 48), q31 = __shfl_xor(p1, 48),
              q32 = __shfl_xor(p2, 48), q33 = __shfl_xor(p3, 48);

        // ---- softmax (each lane has all 16 alphas, fully redundant) ----
        float mx = fmaxf(fmaxf(fmaxf(p0, p1), fmaxf(p2, p3)),
                         fmaxf(fmaxf(fmaxf(q10, q11), fmaxf(q12, q13)),
                               fmaxf(fmaxf(fmaxf(q20, q21), fmaxf(q22, q23)),
                                     fmaxf(fmaxf(q30, q31), fmaxf(q32, q33)))));
        float e0 = __expf(p0 - mx), e1 = __expf(p1 - mx),
              e2 = __expf(p2 - mx), e3 = __expf(p3 - mx);
        float den = e0 + e1 + e2 + e3
                  + __expf(q10 - mx) + __expf(q11 - mx) + __expf(q12 - mx) + __expf(q13 - mx)
                  + __expf(q20 - mx) + __expf(q21 - mx) + __expf(q22 - mx) + __expf(q23 - mx)
                  + __expf(q30 - mx) + __expf(q31 - mx) + __expf(q32 - mx) + __expf(q33 - mx);
        const float inv = 1.0f / den;

        // ---- weighted sum over this quad's 4 rows, then reduce over quads ----
        float o[8];
        #pragma unroll
        for (int ct = 0; ct < 8; ++ct) {
            float v = e0 * acc[ct][0] + e1 * acc[ct][1]
                    + e2 * acc[ct][2] + e3 * acc[ct][3];
            v += __shfl_xor(v, 16);
            v += __shfl_xor(v, 32);
            o[ct] = v;   // complete sum over all 16 rows, replicated
        }

        // quad stores col-tiles 2*quad and 2*quad+1 (static-index select)
        float s0 = 0.f, s1 = 0.f;
        #pragma unroll
        for (int g = 0; g < 4; ++g) {
            if (g == quad) { s0 = o[2 * g]; s1 = o[2 * g + 1]; }
        }
        out[idx * 128 + quad * 32 + c]      = s0 * inv;
        out[idx * 128 + quad * 32 + 16 + c] = s1 * inv;

        ++idx;
    }
    #undef LOAD_TILE
}

extern "C" void kernel_launch(void* const* d_in, const int* in_sizes, int n_in,
                              void* d_out, int out_size, void* d_ws, size_t ws_size,
                              hipStream_t stream) {
    const float* x    = (const float*)d_in[0];
    const float* rel  = (const float*)d_in[1];
    const float* node = (const float*)d_in[2];
    const float* W    = (const float*)d_in[3];
    const float* bias = (const float*)d_in[4];
    float* out = (float*)d_out;
    hipLaunchKernelGGL(nei_attn_kernel, dim3(GRID_), dim3(256), 0, stream,
                       x, rel, node, W, bias, out);
}